// Round 14
// baseline (1466.640 us; speedup 1.0000x reference)
//
#include <hip/hip_runtime.h>
#include <cmath>

#define WIN 64
#define HID 512
#define BATCH 1024
#define KIN 518

typedef _Float16 f16;
typedef _Float16 half8 __attribute__((ext_vector_type(8)));
typedef float f32x4 __attribute__((ext_vector_type(4)));
typedef unsigned short u16x4 __attribute__((ext_vector_type(4)));

struct Sched { int starts[63]; int ends[63]; };
struct TL { int t[8]; int gf[8]; };
struct Targ { int v[32]; };

// ---------------------------------------------------------------------------
// Parallel logsig scan (validated r3-r13) + in-kernel flag table.
// ---------------------------------------------------------------------------
__global__ __launch_bounds__(256)
void logsig_scan(const float* __restrict__ z, Sched sc,
                 ushort* __restrict__ lsh, float scale) {
  __shared__ float zs[3000];
  __shared__ float Cs[20][3];
  __shared__ float wtot[4][6];
  __shared__ float earr[63][6];
  __shared__ short fe_s[1000];
  const int tid = threadIdx.x;
  const int b = blockIdx.x;
  const int ln = tid & 63, wv = tid >> 6;

  const float4* zrow = (const float4*)(z + (size_t)b * 3000);
  for (int i = tid; i < 750; i += 256) ((float4*)zs)[i] = zrow[i];
  for (int i = tid; i < 1000; i += 256) fe_s[i] = -1;
  if (tid == 0) { Cs[0][0] = 0.f; Cs[0][1] = 0.f; Cs[0][2] = 0.f; }
  __syncthreads();
  if (tid < 63) fe_s[sc.ends[tid]] = (short)tid;
  __syncthreads();

  const int p0 = 4 * tid + 1;
  int myfe[4];
#pragma unroll
  for (int i = 0; i < 4; ++i) myfe[i] = (p0 + i <= 999) ? fe_s[p0 + i] : -1;

  float d0 = 0.f, d1 = 0.f, d2 = 0.f, A0 = 0.f, A1 = 0.f, A2 = 0.f;
  if (p0 <= 999) {
    float b0 = 0.f, b1 = 0.f, b2 = 0.f;
#pragma unroll
    for (int i = 0; i < 4; ++i) {
      int p = p0 + i;
      if (p > 999) break;
      float n0 = b0 + zs[p * 3 + 0] * scale;
      float n1 = b1 + zs[p * 3 + 1] * scale;
      float n2 = b2 + zs[p * 3 + 2] * scale;
      A0 += 0.5f * (b0 * n1 - b1 * n0);
      A1 += 0.5f * (b0 * n2 - b2 * n0);
      A2 += 0.5f * (b1 * n2 - b2 * n1);
      b0 = n0; b1 = n1; b2 = n2;
    }
    d0 = b0; d1 = b1; d2 = b2;
  }

#pragma unroll
  for (int off = 1; off < 64; off <<= 1) {
    float e0 = __shfl(d0, ln - off), e1 = __shfl(d1, ln - off), e2 = __shfl(d2, ln - off);
    float eA0 = __shfl(A0, ln - off), eA1 = __shfl(A1, ln - off), eA2 = __shfl(A2, ln - off);
    if (ln >= off) {
      A0 = eA0 + A0 + 0.5f * (e0 * d1 - e1 * d0);
      A1 = eA1 + A1 + 0.5f * (e0 * d2 - e2 * d0);
      A2 = eA2 + A2 + 0.5f * (e1 * d2 - e2 * d1);
      d0 += e0; d1 += e1; d2 += e2;
    }
  }
  if (ln == 63) {
    wtot[wv][0] = d0; wtot[wv][1] = d1; wtot[wv][2] = d2;
    wtot[wv][3] = A0; wtot[wv][4] = A1; wtot[wv][5] = A2;
  }
  __syncthreads();

  float P0 = 0.f, P1 = 0.f, P2 = 0.f, PA0 = 0.f, PA1 = 0.f, PA2 = 0.f;
  for (int w = 0; w < wv; ++w) {
    float t0 = wtot[w][0], t1 = wtot[w][1], t2 = wtot[w][2];
    PA0 = PA0 + wtot[w][3] + 0.5f * (P0 * t1 - P1 * t0);
    PA1 = PA1 + wtot[w][4] + 0.5f * (P0 * t2 - P2 * t0);
    PA2 = PA2 + wtot[w][5] + 0.5f * (P1 * t2 - P2 * t1);
    P0 += t0; P1 += t1; P2 += t2;
  }
  float L0 = __shfl(d0, ln - 1), L1 = __shfl(d1, ln - 1), L2 = __shfl(d2, ln - 1);
  float LA0 = __shfl(A0, ln - 1), LA1 = __shfl(A1, ln - 1), LA2 = __shfl(A2, ln - 1);
  if (ln == 0) { L0 = L1 = L2 = LA0 = LA1 = LA2 = 0.f; }
  float bp0 = P0 + L0, bp1 = P1 + L1, bp2 = P2 + L2;
  float C0 = PA0 + LA0 + 0.5f * (P0 * L1 - P1 * L0);
  float C1 = PA1 + LA1 + 0.5f * (P0 * L2 - P2 * L0);
  float C2 = PA2 + LA2 + 0.5f * (P1 * L2 - P2 * L1);

  if (p0 <= 999) {
#pragma unroll
    for (int i = 0; i < 4; ++i) {
      int p = p0 + i;
      if (p > 999) break;
      float n0 = bp0 + zs[p * 3 + 0] * scale;
      float n1 = bp1 + zs[p * 3 + 1] * scale;
      float n2 = bp2 + zs[p * 3 + 2] * scale;
      C0 += 0.5f * (bp0 * n1 - bp1 * n0);
      C1 += 0.5f * (bp0 * n2 - bp2 * n0);
      C2 += 0.5f * (bp1 * n2 - bp2 * n1);
      bp0 = n0; bp1 = n1; bp2 = n2;
      if (p % 50 == 0) {
        int s = p / 50;
        Cs[s][0] = C0; Cs[s][1] = C1; Cs[s][2] = C2;
      }
      int k = myfe[i];
      if (k >= 0) {
        earr[k][0] = bp0; earr[k][1] = bp1; earr[k][2] = bp2;
        earr[k][3] = C0;  earr[k][4] = C1;  earr[k][5] = C2;
      }
    }
  }
  __syncthreads();

  if (tid < 63) {
    int s = sc.starts[tid] / 50;
    half8 v = {};
    v[0] = (f16)earr[tid][0]; v[1] = (f16)earr[tid][1]; v[2] = (f16)earr[tid][2];
    v[3] = (f16)(earr[tid][3] - Cs[s][0]);
    v[4] = (f16)(earr[tid][4] - Cs[s][1]);
    v[5] = (f16)(earr[tid][5] - Cs[s][2]);
    half8 zz = {};
    half8* d = (half8*)(lsh + ((size_t)(tid + 1) * BATCH + b) * 64);
    d[0] = v;
#pragma unroll
    for (int q = 1; q < 8; ++q) d[q] = zz;
  } else if (tid == 63) {
    half8 zz = {};
    half8* d = (half8*)(lsh + (size_t)b * 64);
#pragma unroll
    for (int q = 0; q < 8; ++q) d[q] = zz;
  }
}

// ---------------------------------------------------------------------------
// One-shot f32 -> f16 convert of all three weight matrices (K zero-padded).
// ---------------------------------------------------------------------------
__global__ __launch_bounds__(256)
void cvt_all(const float* __restrict__ W1, const float* __restrict__ W2,
             const float* __restrict__ W3, ushort* __restrict__ W1h,
             ushort* __restrict__ W2h, ushort* __restrict__ W3h) {
  const int n1 = HID * (576 / 8);
  const int n2 = HID * (HID / 8);
  int i = blockIdx.x * 256 + threadIdx.x;
  const float* src; ushort* dst; int Ks, Kd;
  if (i < n1)           { src = W1; dst = W1h; Ks = KIN; Kd = 576; }
  else if (i < n1 + n2) { src = W2; dst = W2h; Ks = HID; Kd = HID; i -= n1; }
  else if (i < n1 + 2 * n2) { src = W3; dst = W3h; Ks = HID; Kd = HID; i -= n1 + n2; }
  else return;
  int nblk = Kd >> 3;
  int row = i / nblk, k = (i - row * nblk) * 8;
  half8 v;
#pragma unroll
  for (int j = 0; j < 8; ++j) {
    int kk = k + j;
    float f = (kk < Ks) ? src[(size_t)row * Ks + kk] : 0.f;
    v[j] = (f16)f;
  }
  *(half8*)&dst[(size_t)row * Kd + k] = v;
}

__device__ __forceinline__ half8 ld_n(const ushort* p) {
  return *(const half8*)p;
}
__device__ __forceinline__ half8 ld_v(const ushort* p) {   // sc0 (L1-bypass)
  union { f32x4 f; half8 h; } u;
  u.f = *(volatile const f32x4*)p;
  return u.h;
}

// ---------------------------------------------------------------------------
// Fused 3-layer round: ONE launch per gated segment. r13 block decomposition
// (slab x 128-col strip; same-XCD per slab since id%8 == slab%8). Direct-reg
// GEMM (no LDS). Layer handoff: plain stores -> shared XCD L2; consumer
// volatile (sc0) reads; relaxed-only flag sync (no cache maintenance).
// K-order identical to r13 -> bit-identical numerics.
// ---------------------------------------------------------------------------
template<int FIRST>
__global__ __launch_bounds__(256)
void fused3(const ushort* __restrict__ carry, const ushort* __restrict__ lsh,
            TL tl,
            const ushort* __restrict__ W1h, const ushort* __restrict__ W2h,
            const ushort* __restrict__ W3h,
            const float* __restrict__ b1, const float* __restrict__ b2,
            const float* __restrict__ b3,
            ushort* __restrict__ act1, ushort* __restrict__ act2,
            ushort* __restrict__ Hall, int* flags, Targ tg) {
  const int tid = threadIdx.x;
  const int wv = tid >> 6, ln = tid & 63;
  const int l15 = ln & 15, l4 = ln >> 4;
  const int slab = blockIdx.x;                 // XCD = slab % 8 (id%8==slab%8)
  const int bn0 = blockIdx.y * 128;
  const int slot = slab >> 3;
  const int t = tl.t[slot], gated = tl.gf[slot];
  const int b0 = (slab & 7) * 128;             // batch-row base
  const size_t gr0 = (size_t)slab * 128;       // act-row base
  const int xr = (wv >> 1) * 64, nr = (wv & 1) * 64;
  const int targ = tg.v[slab];

  f32x4 acc[4][4];

#define ZACC()                                                                \
  _Pragma("unroll")                                                          \
  for (int mi = 0; mi < 4; ++mi)                                             \
    _Pragma("unroll")                                                        \
    for (int ni = 0; ni < 4; ++ni) acc[mi][ni] = (f32x4){0.f, 0.f, 0.f, 0.f};

#define KSTEP(XP, WP)                                                         \
  do {                                                                        \
    _Pragma("unroll")                                                         \
    for (int kk = 0; kk < 2; ++kk)                                            \
      _Pragma("unroll")                                                       \
      for (int mi = 0; mi < 4; ++mi)                                          \
        _Pragma("unroll")                                                     \
        for (int ni = 0; ni < 4; ++ni)                                        \
          acc[mi][ni] = __builtin_amdgcn_mfma_f32_16x16x32_f16(               \
              (WP)[kk][ni], (XP)[kk][mi], acc[mi][ni], 0, 0, 0);              \
  } while (0)

  // generic K=512 layer: X rows (XBASE + (xrow0+..)*512), W rows at WLD
#define GEMM512(XBASE, XROW0, XVOL, WPTR, WLD)                                \
  _Pragma("unroll 2")                                                         \
  for (int kt = 0; kt < 8; ++kt) {                                            \
    half8 xf[2][4], wf[2][4];                                                 \
    _Pragma("unroll")                                                         \
    for (int kk = 0; kk < 2; ++kk) {                                          \
      _Pragma("unroll")                                                       \
      for (int mi = 0; mi < 4; ++mi) {                                        \
        const ushort* xp = (XBASE) + ((XROW0) + xr + mi * 16 + l15) * (size_t)512 \
                           + kt * 64 + kk * 32 + l4 * 8;                      \
        xf[kk][mi] = (XVOL) ? ld_v(xp) : ld_n(xp);                            \
      }                                                                       \
      _Pragma("unroll")                                                       \
      for (int ni = 0; ni < 4; ++ni)                                          \
        wf[kk][ni] = ld_n((WPTR) + (size_t)(bn0 + nr + ni * 16 + l15) * (WLD) \
                          + kt * 64 + kk * 32 + l4 * 8);                      \
    }                                                                         \
    KSTEP(xf, wf);                                                            \
  }

#define EPILOGUE(ACT, BIAS, STORE_STMT)                                       \
  do {                                                                        \
    _Pragma("unroll")                                                         \
    for (int mi = 0; mi < 4; ++mi) {                                          \
      _Pragma("unroll")                                                       \
      for (int ni = 0; ni < 4; ++ni) {                                        \
        int col = bn0 + nr + ni * 16 + l4 * 4;                                \
        float4 bv = *(const float4*)&(BIAS)[col];                             \
        float bb[4] = {bv.x, bv.y, bv.z, bv.w};                               \
        union { f16 h[4]; u16x4 u; } cv;                                      \
        _Pragma("unroll")                                                     \
        for (int j4 = 0; j4 < 4; ++j4) {                                      \
          float v = acc[mi][ni][j4] + bb[j4];                                 \
          if (ACT == 1) v = fmaxf(v, 0.f);                                    \
          else { float xc = fminf(fmaxf(v, -9.f), 9.f);                       \
                 float e = __expf(2.f * xc); v = (e - 1.f) / (e + 1.f); }     \
          cv.h[j4] = (f16)v;                                                  \
        }                                                                     \
        STORE_STMT;                                                           \
      }                                                                       \
    }                                                                         \
  } while (0)

  // relaxed-only slab sync: own stores drained, then count; no cache maint.
#define SYNCSLAB(FI)                                                          \
  do {                                                                        \
    asm volatile("s_waitcnt vmcnt(0)" ::: "memory");                          \
    __syncthreads();                                                          \
    if (tid == 0) {                                                           \
      __hip_atomic_fetch_add(&flags[FI], 1, __ATOMIC_RELAXED,                 \
                             __HIP_MEMORY_SCOPE_AGENT);                       \
      while (__hip_atomic_load(&flags[FI], __ATOMIC_RELAXED,                  \
                               __HIP_MEMORY_SCOPE_AGENT) < targ)              \
        __builtin_amdgcn_s_sleep(2);                                          \
    }                                                                         \
    __syncthreads();                                                          \
  } while (0)

  // ---------------- layer 1: [h | ls_t] @ W1^T, relu -> act1 ----------------
  ZACC();
  if (!FIRST) { GEMM512(carry, (size_t)b0, 0, W1h, 576); }
  {  // ls tail: k in [512, 576)
    half8 xf[2][4], wf[2][4];
#pragma unroll
    for (int kk = 0; kk < 2; ++kk) {
#pragma unroll
      for (int mi = 0; mi < 4; ++mi)
        xf[kk][mi] = ld_n(lsh + ((size_t)t * BATCH + b0 + xr + mi * 16 + l15) * 64
                          + kk * 32 + l4 * 8);
#pragma unroll
      for (int ni = 0; ni < 4; ++ni)
        wf[kk][ni] = ld_n(W1h + (size_t)(bn0 + nr + ni * 16 + l15) * 576
                          + 512 + kk * 32 + l4 * 8);
    }
    KSTEP(xf, wf);
  }
  EPILOGUE(1, b1,
    *(u16x4*)&act1[(gr0 + xr + mi * 16 + l15) * 512 + col] = cv.u);
  SYNCSLAB(slab);

  // ---------------- layer 2: relu -> act2 ----------------
  ZACC();
  GEMM512(act1, gr0, 1, W2h, 512);
  EPILOGUE(1, b2,
    *(u16x4*)&act2[(gr0 + xr + mi * 16 + l15) * 512 + col] = cv.u);
  SYNCSLAB(64 + slab);

  // ---------------- layer 3: tanh -> Hall[t] ----------------
  ZACC();
  GEMM512(act2, gr0, 1, W3h, 512);
  EPILOGUE(2, b3,
    { size_t hrow = (size_t)t * BATCH + b0 + xr + mi * 16 + l15;
      u16x4* dst = (u16x4*)&Hall[hrow * 512 + col];
      if (gated) *dst = cv.u;
      else       __builtin_nontemporal_store(cv.u, dst); });
#undef ZACC
#undef KSTEP
#undef GEMM512
#undef EPILOGUE
#undef SYNCSLAB
}

// ---------------------------------------------------------------------------
// out[b, t, :] = Hall[t][b][:] @ Wout^T. 4 lanes per row, shfl reduce.
// ---------------------------------------------------------------------------
__global__ __launch_bounds__(256)
void out_k(const ushort* __restrict__ Hall, const float* __restrict__ Wout,
           float* __restrict__ out) {
  const int tid = threadIdx.x;
  const int lane4 = tid & 3;
  const int row = blockIdx.x * 64 + (tid >> 2);   // t*1024 + b
  const int t = row >> 10, b = row & 1023;
  const ushort* hb = Hall + (size_t)row * HID;
  float a0 = 0.f, a1 = 0.f, a2 = 0.f;
#pragma unroll 4
  for (int q = 0; q < 16; ++q) {
    int k = (q * 4 + lane4) * 8;
    half8 hv8 = *(const half8*)&hb[k];
#pragma unroll
    for (int j = 0; j < 8; ++j) {
      float h = (float)hv8[j];
      a0 += h * Wout[k + j];
      a1 += h * Wout[512 + k + j];
      a2 += h * Wout[1024 + k + j];
    }
  }
  a0 += __shfl_xor(a0, 1); a0 += __shfl_xor(a0, 2);
  a1 += __shfl_xor(a1, 1); a1 += __shfl_xor(a1, 2);
  a2 += __shfl_xor(a2, 1); a2 += __shfl_xor(a2, 2);
  if (lane4 == 0) {
    float* o = out + ((size_t)b * WIN + t) * 3;
    o[0] = a0; o[1] = a1; o[2] = a2;
  }
}

// ---------------------------------------------------------------------------
extern "C" void kernel_launch(void* const* d_in, const int* in_sizes, int n_in,
                              void* d_out, int out_size, void* d_ws, size_t ws_size,
                              hipStream_t stream) {
  (void)n_in; (void)out_size; (void)ws_size; (void)in_sizes;
  const float* z    = (const float*)d_in[0];
  const float* W1   = (const float*)d_in[1];
  const float* b1   = (const float*)d_in[2];
  const float* W2   = (const float*)d_in[3];
  const float* b2   = (const float*)d_in[4];
  const float* W3   = (const float*)d_in[5];
  const float* b3   = (const float*)d_in[6];
  const float* Wout = (const float*)d_in[7];
  float* out = (float*)d_out;

  // ---- replicate _static_schedule exactly (numpy linspace doubles) ----
  double tb[1000], tt[64], tu[20];
  {
    double sb = 1.0 / 999.0; for (int i = 0; i < 1000; ++i) tb[i] = i * sb; tb[999] = 1.0;
    double st = 1.0 / 63.0;  for (int k = 0; k < 64; ++k)  tt[k] = k * st;  tt[63] = 1.0;
    for (int j = 0; j < 20; ++j) tu[j] = tb[50 * j];
  }
  auto ssr = [](const double* a, int n, double v) -> int {
    int lo = 0, hi = n;
    while (lo < hi) { int mid = (lo + hi) >> 1; if (a[mid] <= v) lo = mid + 1; else hi = mid; }
    return lo - 1;
  };
  Sched sc; int gates[64];
  {
    int u_indices[20];
    for (int j = 0; j < 20; ++j) u_indices[j] = ssr(tb, 1000, tu[j]);
    double u_times[80]; int nut = 0; int last = -1;
    for (int k = 1; k < 64; ++k) {
      int it = ssr(tb, 1000, tt[k]);
      int iu = ssr(tu, 20, tt[k]); if (iu < 0) iu = 0;
      if (iu != last) { u_times[nut++] = tu[iu]; last = iu; }
      sc.starts[k - 1] = u_indices[iu];
      sc.ends[k - 1] = it;
    }
    u_times[nut++] = tt[63];
    int qh = 0;
    for (int k = 0; k < 64; ++k) {
      if (qh < nut && tt[k] >= u_times[qh]) { ++qh; gates[k] = 1; } else gates[k] = 0;
    }
  }
  int seg[64], g[64], ng = 0, jlast = -1;
  for (int t = 0; t < WIN; ++t) {
    seg[t] = jlast;
    if (gates[t]) { g[ng] = t; jlast = ng; ++ng; }
  }

  // ---- workspace carve ----
  char* p = (char*)d_ws;
  int* flags   = (int*)p;    p += 128 * 4;
  ushort* lsh  = (ushort*)p; p += (size_t)WIN * BATCH * 64 * 2;        // 8.4 MB
  ushort* W1h  = (ushort*)p; p += (size_t)HID * 576 * 2;
  ushort* W2h  = (ushort*)p; p += (size_t)HID * HID * 2;
  ushort* W3h  = (ushort*)p; p += (size_t)HID * HID * 2;
  ushort* Hall = (ushort*)p; p += (size_t)WIN * BATCH * HID * 2;       // 67 MB
  ushort* act1 = (ushort*)p; p += (size_t)4 * BATCH * HID * 2;         // 4.2 MB
  ushort* act2 = (ushort*)p; p += (size_t)4 * BATCH * HID * 2;

  hipMemsetAsync(flags, 0, 128 * 4, stream);

  float scale = (float)std::sqrt(1.0 / 999.0);
  logsig_scan<<<BATCH, 256, 0, stream>>>(z, sc, lsh, scale);
  cvt_all<<<(HID * 72 + 2 * HID * 64 + 255) / 256, 256, 0, stream>>>(
      W1, W2, W3, W1h, W2h, W3h);

  // ---- serial per-segment rounds: ONE fused 3-layer launch each ----
  Targ tg; for (int i = 0; i < 32; ++i) tg.v[i] = 0;
  for (int r = 0; r < ng; ++r) {
    TL tlr; int cnt = 0;
    for (int t = 0; t < WIN && cnt < 4; ++t)
      if (seg[t] == r - 1) tlr.t[cnt++] = t;
    if (cnt == 0) continue;
    for (int i = cnt; i < 8; ++i) tlr.t[i] = tlr.t[0];
    for (int i = 0; i < 8; ++i) tlr.gf[i] = (tlr.t[i] == g[r]) ? 1 : 0;
    for (int s = 0; s < cnt * 8; ++s) tg.v[s] += 4;     // monotonic targets
    const ushort* carry = (r == 0) ? nullptr : Hall + (size_t)g[r - 1] * (BATCH * HID);
    dim3 gg(cnt * 8, 4), gb(256);
    if (r == 0)
      fused3<1><<<gg, gb, 0, stream>>>(carry, lsh, tlr, W1h, W2h, W3h,
                                       b1, b2, b3, act1, act2, Hall, flags, tg);
    else
      fused3<0><<<gg, gb, 0, stream>>>(carry, lsh, tlr, W1h, W2h, W3h,
                                       b1, b2, b3, act1, act2, Hall, flags, tg);
  }

  out_k<<<WIN * BATCH / 64, 256, 0, stream>>>(Hall, Wout, out);
}

// Round 15
// 1328.652 us; speedup vs baseline: 1.1039x; 1.1039x over previous
//
#include <hip/hip_runtime.h>
#include <cmath>

#define WIN 64
#define HID 512
#define BATCH 1024
#define KIN 518

typedef _Float16 f16;
typedef _Float16 half8 __attribute__((ext_vector_type(8)));
typedef float f32x4 __attribute__((ext_vector_type(4)));
typedef unsigned short u16x4 __attribute__((ext_vector_type(4)));

struct Sched { int starts[63]; int ends[63]; };
struct TL { int t[8]; int gf[8]; };
struct Targ { int v[32]; };

// ---------------------------------------------------------------------------
// Parallel logsig scan (validated r3-r14) + in-kernel flag table.
// ---------------------------------------------------------------------------
__global__ __launch_bounds__(256)
void logsig_scan(const float* __restrict__ z, Sched sc,
                 ushort* __restrict__ lsh, float scale) {
  __shared__ float zs[3000];
  __shared__ float Cs[20][3];
  __shared__ float wtot[4][6];
  __shared__ float earr[63][6];
  __shared__ short fe_s[1000];
  const int tid = threadIdx.x;
  const int b = blockIdx.x;
  const int ln = tid & 63, wv = tid >> 6;

  const float4* zrow = (const float4*)(z + (size_t)b * 3000);
  for (int i = tid; i < 750; i += 256) ((float4*)zs)[i] = zrow[i];
  for (int i = tid; i < 1000; i += 256) fe_s[i] = -1;
  if (tid == 0) { Cs[0][0] = 0.f; Cs[0][1] = 0.f; Cs[0][2] = 0.f; }
  __syncthreads();
  if (tid < 63) fe_s[sc.ends[tid]] = (short)tid;
  __syncthreads();

  const int p0 = 4 * tid + 1;
  int myfe[4];
#pragma unroll
  for (int i = 0; i < 4; ++i) myfe[i] = (p0 + i <= 999) ? fe_s[p0 + i] : -1;

  float d0 = 0.f, d1 = 0.f, d2 = 0.f, A0 = 0.f, A1 = 0.f, A2 = 0.f;
  if (p0 <= 999) {
    float b0 = 0.f, b1 = 0.f, b2 = 0.f;
#pragma unroll
    for (int i = 0; i < 4; ++i) {
      int p = p0 + i;
      if (p > 999) break;
      float n0 = b0 + zs[p * 3 + 0] * scale;
      float n1 = b1 + zs[p * 3 + 1] * scale;
      float n2 = b2 + zs[p * 3 + 2] * scale;
      A0 += 0.5f * (b0 * n1 - b1 * n0);
      A1 += 0.5f * (b0 * n2 - b2 * n0);
      A2 += 0.5f * (b1 * n2 - b2 * n1);
      b0 = n0; b1 = n1; b2 = n2;
    }
    d0 = b0; d1 = b1; d2 = b2;
  }

#pragma unroll
  for (int off = 1; off < 64; off <<= 1) {
    float e0 = __shfl(d0, ln - off), e1 = __shfl(d1, ln - off), e2 = __shfl(d2, ln - off);
    float eA0 = __shfl(A0, ln - off), eA1 = __shfl(A1, ln - off), eA2 = __shfl(A2, ln - off);
    if (ln >= off) {
      A0 = eA0 + A0 + 0.5f * (e0 * d1 - e1 * d0);
      A1 = eA1 + A1 + 0.5f * (e0 * d2 - e2 * d0);
      A2 = eA2 + A2 + 0.5f * (e1 * d2 - e2 * d1);
      d0 += e0; d1 += e1; d2 += e2;
    }
  }
  if (ln == 63) {
    wtot[wv][0] = d0; wtot[wv][1] = d1; wtot[wv][2] = d2;
    wtot[wv][3] = A0; wtot[wv][4] = A1; wtot[wv][5] = A2;
  }
  __syncthreads();

  float P0 = 0.f, P1 = 0.f, P2 = 0.f, PA0 = 0.f, PA1 = 0.f, PA2 = 0.f;
  for (int w = 0; w < wv; ++w) {
    float t0 = wtot[w][0], t1 = wtot[w][1], t2 = wtot[w][2];
    PA0 = PA0 + wtot[w][3] + 0.5f * (P0 * t1 - P1 * t0);
    PA1 = PA1 + wtot[w][4] + 0.5f * (P0 * t2 - P2 * t0);
    PA2 = PA2 + wtot[w][5] + 0.5f * (P1 * t2 - P2 * t1);
    P0 += t0; P1 += t1; P2 += t2;
  }
  float L0 = __shfl(d0, ln - 1), L1 = __shfl(d1, ln - 1), L2 = __shfl(d2, ln - 1);
  float LA0 = __shfl(A0, ln - 1), LA1 = __shfl(A1, ln - 1), LA2 = __shfl(A2, ln - 1);
  if (ln == 0) { L0 = L1 = L2 = LA0 = LA1 = LA2 = 0.f; }
  float bp0 = P0 + L0, bp1 = P1 + L1, bp2 = P2 + L2;
  float C0 = PA0 + LA0 + 0.5f * (P0 * L1 - P1 * L0);
  float C1 = PA1 + LA1 + 0.5f * (P0 * L2 - P2 * L0);
  float C2 = PA2 + LA2 + 0.5f * (P1 * L2 - P2 * L1);

  if (p0 <= 999) {
#pragma unroll
    for (int i = 0; i < 4; ++i) {
      int p = p0 + i;
      if (p > 999) break;
      float n0 = bp0 + zs[p * 3 + 0] * scale;
      float n1 = bp1 + zs[p * 3 + 1] * scale;
      float n2 = bp2 + zs[p * 3 + 2] * scale;
      C0 += 0.5f * (bp0 * n1 - bp1 * n0);
      C1 += 0.5f * (bp0 * n2 - bp2 * n0);
      C2 += 0.5f * (bp1 * n2 - bp2 * n1);
      bp0 = n0; bp1 = n1; bp2 = n2;
      if (p % 50 == 0) {
        int s = p / 50;
        Cs[s][0] = C0; Cs[s][1] = C1; Cs[s][2] = C2;
      }
      int k = myfe[i];
      if (k >= 0) {
        earr[k][0] = bp0; earr[k][1] = bp1; earr[k][2] = bp2;
        earr[k][3] = C0;  earr[k][4] = C1;  earr[k][5] = C2;
      }
    }
  }
  __syncthreads();

  if (tid < 63) {
    int s = sc.starts[tid] / 50;
    half8 v = {};
    v[0] = (f16)earr[tid][0]; v[1] = (f16)earr[tid][1]; v[2] = (f16)earr[tid][2];
    v[3] = (f16)(earr[tid][3] - Cs[s][0]);
    v[4] = (f16)(earr[tid][4] - Cs[s][1]);
    v[5] = (f16)(earr[tid][5] - Cs[s][2]);
    half8 zz = {};
    half8* d = (half8*)(lsh + ((size_t)(tid + 1) * BATCH + b) * 64);
    d[0] = v;
#pragma unroll
    for (int q = 1; q < 8; ++q) d[q] = zz;
  } else if (tid == 63) {
    half8 zz = {};
    half8* d = (half8*)(lsh + (size_t)b * 64);
#pragma unroll
    for (int q = 0; q < 8; ++q) d[q] = zz;
  }
}

// ---------------------------------------------------------------------------
// One-shot f32 -> f16 convert of all three weight matrices (K zero-padded).
// ---------------------------------------------------------------------------
__global__ __launch_bounds__(256)
void cvt_all(const float* __restrict__ W1, const float* __restrict__ W2,
             const float* __restrict__ W3, ushort* __restrict__ W1h,
             ushort* __restrict__ W2h, ushort* __restrict__ W3h) {
  const int n1 = HID * (576 / 8);
  const int n2 = HID * (HID / 8);
  int i = blockIdx.x * 256 + threadIdx.x;
  const float* src; ushort* dst; int Ks, Kd;
  if (i < n1)           { src = W1; dst = W1h; Ks = KIN; Kd = 576; }
  else if (i < n1 + n2) { src = W2; dst = W2h; Ks = HID; Kd = HID; i -= n1; }
  else if (i < n1 + 2 * n2) { src = W3; dst = W3h; Ks = HID; Kd = HID; i -= n1 + n2; }
  else return;
  int nblk = Kd >> 3;
  int row = i / nblk, k = (i - row * nblk) * 8;
  half8 v;
#pragma unroll
  for (int j = 0; j < 8; ++j) {
    int kk = k + j;
    float f = (kk < Ks) ? src[(size_t)row * Ks + kk] : 0.f;
    v[j] = (f16)f;
  }
  *(half8*)&dst[(size_t)row * Kd + k] = v;
}

__device__ __forceinline__ half8 ld_n(const ushort* p) {
  return *(const half8*)p;
}

// ---------------------------------------------------------------------------
// Fused 3-layer round: ONE launch per gated segment. Blocks (slab x 128-col
// strip); all 4 strips of a slab on ONE XCD (id%8 == slab%8). Direct-reg
// GEMM. Layer handoff: PLAIN stores (write-through to XCD L2) -> vmcnt(0) ->
// relaxed L2-atomic flag -> consumer PLAIN loads (L1 invalidated at dispatch,
// first touch => L2 hit). No volatile (r14's sc1 reads bypassed L2 -> HBM).
// K-order identical to r13 -> bit-identical numerics (r14 verified).
// ---------------------------------------------------------------------------
template<int FIRST>
__global__ __launch_bounds__(256)
void fused3(const ushort* __restrict__ carry, const ushort* __restrict__ lsh,
            TL tl,
            const ushort* __restrict__ W1h, const ushort* __restrict__ W2h,
            const ushort* __restrict__ W3h,
            const float* __restrict__ b1, const float* __restrict__ b2,
            const float* __restrict__ b3,
            ushort* __restrict__ act1, ushort* __restrict__ act2,
            ushort* __restrict__ Hall, int* flags, Targ tg) {
  const int tid = threadIdx.x;
  const int wv = tid >> 6, ln = tid & 63;
  const int l15 = ln & 15, l4 = ln >> 4;
  const int slab = blockIdx.x;                 // XCD = slab % 8 (id%8==slab%8)
  const int bn0 = blockIdx.y * 128;
  const int slot = slab >> 3;
  const int t = tl.t[slot], gated = tl.gf[slot];
  const int b0 = (slab & 7) * 128;             // batch-row base
  const size_t gr0 = (size_t)slab * 128;       // act-row base
  const int xr = (wv >> 1) * 64, nr = (wv & 1) * 64;
  const int targ = tg.v[slab];

  f32x4 acc[4][4];

#define ZACC()                                                                \
  _Pragma("unroll")                                                          \
  for (int mi = 0; mi < 4; ++mi)                                             \
    _Pragma("unroll")                                                        \
    for (int ni = 0; ni < 4; ++ni) acc[mi][ni] = (f32x4){0.f, 0.f, 0.f, 0.f};

#define KSTEP(XP, WP)                                                         \
  do {                                                                        \
    _Pragma("unroll")                                                         \
    for (int kk = 0; kk < 2; ++kk)                                            \
      _Pragma("unroll")                                                       \
      for (int mi = 0; mi < 4; ++mi)                                          \
        _Pragma("unroll")                                                     \
        for (int ni = 0; ni < 4; ++ni)                                        \
          acc[mi][ni] = __builtin_amdgcn_mfma_f32_16x16x32_f16(               \
              (WP)[kk][ni], (XP)[kk][mi], acc[mi][ni], 0, 0, 0);              \
  } while (0)

#define GEMM512(XBASE, XROW0, WPTR, WLD)                                      \
  _Pragma("unroll 2")                                                         \
  for (int kt = 0; kt < 8; ++kt) {                                            \
    half8 xf[2][4], wf[2][4];                                                 \
    _Pragma("unroll")                                                         \
    for (int kk = 0; kk < 2; ++kk) {                                          \
      _Pragma("unroll")                                                       \
      for (int mi = 0; mi < 4; ++mi)                                          \
        xf[kk][mi] = ld_n((XBASE) + ((XROW0) + xr + mi * 16 + l15) * (size_t)512 \
                          + kt * 64 + kk * 32 + l4 * 8);                      \
      _Pragma("unroll")                                                       \
      for (int ni = 0; ni < 4; ++ni)                                          \
        wf[kk][ni] = ld_n((WPTR) + (size_t)(bn0 + nr + ni * 16 + l15) * (WLD) \
                          + kt * 64 + kk * 32 + l4 * 8);                      \
    }                                                                         \
    KSTEP(xf, wf);                                                            \
  }

#define EPILOGUE(ACT, BIAS, STORE_STMT)                                       \
  do {                                                                        \
    _Pragma("unroll")                                                         \
    for (int mi = 0; mi < 4; ++mi) {                                          \
      _Pragma("unroll")                                                       \
      for (int ni = 0; ni < 4; ++ni) {                                        \
        int col = bn0 + nr + ni * 16 + l4 * 4;                                \
        float4 bv = *(const float4*)&(BIAS)[col];                             \
        float bb[4] = {bv.x, bv.y, bv.z, bv.w};                               \
        union { f16 h[4]; u16x4 u; } cv;                                      \
        _Pragma("unroll")                                                     \
        for (int j4 = 0; j4 < 4; ++j4) {                                      \
          float v = acc[mi][ni][j4] + bb[j4];                                 \
          if (ACT == 1) v = fmaxf(v, 0.f);                                    \
          else { float xc = fminf(fmaxf(v, -9.f), 9.f);                       \
                 float e = __expf(2.f * xc); v = (e - 1.f) / (e + 1.f); }     \
          cv.h[j4] = (f16)v;                                                  \
        }                                                                     \
        STORE_STMT;                                                           \
      }                                                                       \
    }                                                                         \
  } while (0)

#define SYNCSLAB(FI)                                                          \
  do {                                                                        \
    asm volatile("s_waitcnt vmcnt(0)" ::: "memory");                          \
    __syncthreads();                                                          \
    if (tid == 0) {                                                           \
      __hip_atomic_fetch_add(&flags[FI], 1, __ATOMIC_RELAXED,                 \
                             __HIP_MEMORY_SCOPE_AGENT);                       \
      while (__hip_atomic_load(&flags[FI], __ATOMIC_RELAXED,                  \
                               __HIP_MEMORY_SCOPE_AGENT) < targ)              \
        __builtin_amdgcn_s_sleep(2);                                          \
    }                                                                         \
    __syncthreads();                                                          \
  } while (0)

  // ---------------- layer 1: [h | ls_t] @ W1^T, relu -> act1 ----------------
  ZACC();
  if (!FIRST) { GEMM512(carry, (size_t)b0, W1h, 576); }
  {  // ls tail: k in [512, 576)
    half8 xf[2][4], wf[2][4];
#pragma unroll
    for (int kk = 0; kk < 2; ++kk) {
#pragma unroll
      for (int mi = 0; mi < 4; ++mi)
        xf[kk][mi] = ld_n(lsh + ((size_t)t * BATCH + b0 + xr + mi * 16 + l15) * 64
                          + kk * 32 + l4 * 8);
#pragma unroll
      for (int ni = 0; ni < 4; ++ni)
        wf[kk][ni] = ld_n(W1h + (size_t)(bn0 + nr + ni * 16 + l15) * 576
                          + 512 + kk * 32 + l4 * 8);
    }
    KSTEP(xf, wf);
  }
  EPILOGUE(1, b1,
    *(u16x4*)&act1[(gr0 + xr + mi * 16 + l15) * 512 + col] = cv.u);
  SYNCSLAB(slab);

  // ---------------- layer 2: relu -> act2 ----------------
  ZACC();
  GEMM512(act1, gr0, W2h, 512);
  EPILOGUE(1, b2,
    *(u16x4*)&act2[(gr0 + xr + mi * 16 + l15) * 512 + col] = cv.u);
  SYNCSLAB(64 + slab);

  // ---------------- layer 3: tanh -> Hall[t] ----------------
  ZACC();
  GEMM512(act2, gr0, W3h, 512);
  EPILOGUE(2, b3,
    { size_t hrow = (size_t)t * BATCH + b0 + xr + mi * 16 + l15;
      u16x4* dst = (u16x4*)&Hall[hrow * 512 + col];
      if (gated) *dst = cv.u;
      else       __builtin_nontemporal_store(cv.u, dst); });
#undef ZACC
#undef KSTEP
#undef GEMM512
#undef EPILOGUE
#undef SYNCSLAB
}

// ---------------------------------------------------------------------------
// out[b, t, :] = Hall[t][b][:] @ Wout^T. 4 lanes per row, shfl reduce.
// ---------------------------------------------------------------------------
__global__ __launch_bounds__(256)
void out_k(const ushort* __restrict__ Hall, const float* __restrict__ Wout,
           float* __restrict__ out) {
  const int tid = threadIdx.x;
  const int lane4 = tid & 3;
  const int row = blockIdx.x * 64 + (tid >> 2);   // t*1024 + b
  const int t = row >> 10, b = row & 1023;
  const ushort* hb = Hall + (size_t)row * HID;
  float a0 = 0.f, a1 = 0.f, a2 = 0.f;
#pragma unroll 4
  for (int q = 0; q < 16; ++q) {
    int k = (q * 4 + lane4) * 8;
    half8 hv8 = *(const half8*)&hb[k];
#pragma unroll
    for (int j = 0; j < 8; ++j) {
      float h = (float)hv8[j];
      a0 += h * Wout[k + j];
      a1 += h * Wout[512 + k + j];
      a2 += h * Wout[1024 + k + j];
    }
  }
  a0 += __shfl_xor(a0, 1); a0 += __shfl_xor(a0, 2);
  a1 += __shfl_xor(a1, 1); a1 += __shfl_xor(a1, 2);
  a2 += __shfl_xor(a2, 1); a2 += __shfl_xor(a2, 2);
  if (lane4 == 0) {
    float* o = out + ((size_t)b * WIN + t) * 3;
    o[0] = a0; o[1] = a1; o[2] = a2;
  }
}

// ---------------------------------------------------------------------------
extern "C" void kernel_launch(void* const* d_in, const int* in_sizes, int n_in,
                              void* d_out, int out_size, void* d_ws, size_t ws_size,
                              hipStream_t stream) {
  (void)n_in; (void)out_size; (void)ws_size; (void)in_sizes;
  const float* z    = (const float*)d_in[0];
  const float* W1   = (const float*)d_in[1];
  const float* b1   = (const float*)d_in[2];
  const float* W2   = (const float*)d_in[3];
  const float* b2   = (const float*)d_in[4];
  const float* W3   = (const float*)d_in[5];
  const float* b3   = (const float*)d_in[6];
  const float* Wout = (const float*)d_in[7];
  float* out = (float*)d_out;

  // ---- replicate _static_schedule exactly (numpy linspace doubles) ----
  double tb[1000], tt[64], tu[20];
  {
    double sb = 1.0 / 999.0; for (int i = 0; i < 1000; ++i) tb[i] = i * sb; tb[999] = 1.0;
    double st = 1.0 / 63.0;  for (int k = 0; k < 64; ++k)  tt[k] = k * st;  tt[63] = 1.0;
    for (int j = 0; j < 20; ++j) tu[j] = tb[50 * j];
  }
  auto ssr = [](const double* a, int n, double v) -> int {
    int lo = 0, hi = n;
    while (lo < hi) { int mid = (lo + hi) >> 1; if (a[mid] <= v) lo = mid + 1; else hi = mid; }
    return lo - 1;
  };
  Sched sc; int gates[64];
  {
    int u_indices[20];
    for (int j = 0; j < 20; ++j) u_indices[j] = ssr(tb, 1000, tu[j]);
    double u_times[80]; int nut = 0; int last = -1;
    for (int k = 1; k < 64; ++k) {
      int it = ssr(tb, 1000, tt[k]);
      int iu = ssr(tu, 20, tt[k]); if (iu < 0) iu = 0;
      if (iu != last) { u_times[nut++] = tu[iu]; last = iu; }
      sc.starts[k - 1] = u_indices[iu];
      sc.ends[k - 1] = it;
    }
    u_times[nut++] = tt[63];
    int qh = 0;
    for (int k = 0; k < 64; ++k) {
      if (qh < nut && tt[k] >= u_times[qh]) { ++qh; gates[k] = 1; } else gates[k] = 0;
    }
  }
  int seg[64], g[64], ng = 0, jlast = -1;
  for (int t = 0; t < WIN; ++t) {
    seg[t] = jlast;
    if (gates[t]) { g[ng] = t; jlast = ng; ++ng; }
  }

  // ---- workspace carve ----
  char* p = (char*)d_ws;
  int* flags   = (int*)p;    p += 128 * 4;
  ushort* lsh  = (ushort*)p; p += (size_t)WIN * BATCH * 64 * 2;        // 8.4 MB
  ushort* W1h  = (ushort*)p; p += (size_t)HID * 576 * 2;
  ushort* W2h  = (ushort*)p; p += (size_t)HID * HID * 2;
  ushort* W3h  = (ushort*)p; p += (size_t)HID * HID * 2;
  ushort* Hall = (ushort*)p; p += (size_t)WIN * BATCH * HID * 2;       // 67 MB
  ushort* act1 = (ushort*)p; p += (size_t)4 * BATCH * HID * 2;         // 4.2 MB
  ushort* act2 = (ushort*)p; p += (size_t)4 * BATCH * HID * 2;

  hipMemsetAsync(flags, 0, 128 * 4, stream);

  float scale = (float)std::sqrt(1.0 / 999.0);
  logsig_scan<<<BATCH, 256, 0, stream>>>(z, sc, lsh, scale);
  cvt_all<<<(HID * 72 + 2 * HID * 64 + 255) / 256, 256, 0, stream>>>(
      W1, W2, W3, W1h, W2h, W3h);

  // ---- serial per-segment rounds: ONE fused 3-layer launch each ----
  Targ tg; for (int i = 0; i < 32; ++i) tg.v[i] = 0;
  for (int r = 0; r < ng; ++r) {
    TL tlr; int cnt = 0;
    for (int t = 0; t < WIN && cnt < 4; ++t)
      if (seg[t] == r - 1) tlr.t[cnt++] = t;
    if (cnt == 0) continue;
    for (int i = cnt; i < 8; ++i) tlr.t[i] = tlr.t[0];
    for (int i = 0; i < 8; ++i) tlr.gf[i] = (tlr.t[i] == g[r]) ? 1 : 0;
    for (int s = 0; s < cnt * 8; ++s) tg.v[s] += 4;     // monotonic targets
    const ushort* carry = (r == 0) ? nullptr : Hall + (size_t)g[r - 1] * (BATCH * HID);
    dim3 gg(cnt * 8, 4), gb(256);
    if (r == 0)
      fused3<1><<<gg, gb, 0, stream>>>(carry, lsh, tlr, W1h, W2h, W3h,
                                       b1, b2, b3, act1, act2, Hall, flags, tg);
    else
      fused3<0><<<gg, gb, 0, stream>>>(carry, lsh, tlr, W1h, W2h, W3h,
                                       b1, b2, b3, act1, act2, Hall, flags, tg);
  }

  out_k<<<WIN * BATCH / 64, 256, 0, stream>>>(Hall, Wout, out);
}

// Round 16
// 603.521 us; speedup vs baseline: 2.4301x; 2.2015x over previous
//
#include <hip/hip_runtime.h>
#include <cmath>

#define WIN 64
#define HID 512
#define BATCH 1024
#define KIN 518

typedef _Float16 f16;
typedef _Float16 half8 __attribute__((ext_vector_type(8)));
typedef float f32x4 __attribute__((ext_vector_type(4)));
typedef unsigned short u16x4 __attribute__((ext_vector_type(4)));

struct Sched { int starts[63]; int ends[63]; };
struct TL { int t[8]; int gf[8]; };
struct Targ { int v[32]; };

// ---------------------------------------------------------------------------
// Parallel logsig scan (validated r3-r15) + in-kernel flag table.
// ---------------------------------------------------------------------------
__global__ __launch_bounds__(256)
void logsig_scan(const float* __restrict__ z, Sched sc,
                 ushort* __restrict__ lsh, float scale) {
  __shared__ float zs[3000];
  __shared__ float Cs[20][3];
  __shared__ float wtot[4][6];
  __shared__ float earr[63][6];
  __shared__ short fe_s[1000];
  const int tid = threadIdx.x;
  const int b = blockIdx.x;
  const int ln = tid & 63, wv = tid >> 6;

  const float4* zrow = (const float4*)(z + (size_t)b * 3000);
  for (int i = tid; i < 750; i += 256) ((float4*)zs)[i] = zrow[i];
  for (int i = tid; i < 1000; i += 256) fe_s[i] = -1;
  if (tid == 0) { Cs[0][0] = 0.f; Cs[0][1] = 0.f; Cs[0][2] = 0.f; }
  __syncthreads();
  if (tid < 63) fe_s[sc.ends[tid]] = (short)tid;
  __syncthreads();

  const int p0 = 4 * tid + 1;
  int myfe[4];
#pragma unroll
  for (int i = 0; i < 4; ++i) myfe[i] = (p0 + i <= 999) ? fe_s[p0 + i] : -1;

  float d0 = 0.f, d1 = 0.f, d2 = 0.f, A0 = 0.f, A1 = 0.f, A2 = 0.f;
  if (p0 <= 999) {
    float b0 = 0.f, b1 = 0.f, b2 = 0.f;
#pragma unroll
    for (int i = 0; i < 4; ++i) {
      int p = p0 + i;
      if (p > 999) break;
      float n0 = b0 + zs[p * 3 + 0] * scale;
      float n1 = b1 + zs[p * 3 + 1] * scale;
      float n2 = b2 + zs[p * 3 + 2] * scale;
      A0 += 0.5f * (b0 * n1 - b1 * n0);
      A1 += 0.5f * (b0 * n2 - b2 * n0);
      A2 += 0.5f * (b1 * n2 - b2 * n1);
      b0 = n0; b1 = n1; b2 = n2;
    }
    d0 = b0; d1 = b1; d2 = b2;
  }

#pragma unroll
  for (int off = 1; off < 64; off <<= 1) {
    float e0 = __shfl(d0, ln - off), e1 = __shfl(d1, ln - off), e2 = __shfl(d2, ln - off);
    float eA0 = __shfl(A0, ln - off), eA1 = __shfl(A1, ln - off), eA2 = __shfl(A2, ln - off);
    if (ln >= off) {
      A0 = eA0 + A0 + 0.5f * (e0 * d1 - e1 * d0);
      A1 = eA1 + A1 + 0.5f * (e0 * d2 - e2 * d0);
      A2 = eA2 + A2 + 0.5f * (e1 * d2 - e2 * d1);
      d0 += e0; d1 += e1; d2 += e2;
    }
  }
  if (ln == 63) {
    wtot[wv][0] = d0; wtot[wv][1] = d1; wtot[wv][2] = d2;
    wtot[wv][3] = A0; wtot[wv][4] = A1; wtot[wv][5] = A2;
  }
  __syncthreads();

  float P0 = 0.f, P1 = 0.f, P2 = 0.f, PA0 = 0.f, PA1 = 0.f, PA2 = 0.f;
  for (int w = 0; w < wv; ++w) {
    float t0 = wtot[w][0], t1 = wtot[w][1], t2 = wtot[w][2];
    PA0 = PA0 + wtot[w][3] + 0.5f * (P0 * t1 - P1 * t0);
    PA1 = PA1 + wtot[w][4] + 0.5f * (P0 * t2 - P2 * t0);
    PA2 = PA2 + wtot[w][5] + 0.5f * (P1 * t2 - P2 * t1);
    P0 += t0; P1 += t1; P2 += t2;
  }
  float L0 = __shfl(d0, ln - 1), L1 = __shfl(d1, ln - 1), L2 = __shfl(d2, ln - 1);
  float LA0 = __shfl(A0, ln - 1), LA1 = __shfl(A1, ln - 1), LA2 = __shfl(A2, ln - 1);
  if (ln == 0) { L0 = L1 = L2 = LA0 = LA1 = LA2 = 0.f; }
  float bp0 = P0 + L0, bp1 = P1 + L1, bp2 = P2 + L2;
  float C0 = PA0 + LA0 + 0.5f * (P0 * L1 - P1 * L0);
  float C1 = PA1 + LA1 + 0.5f * (P0 * L2 - P2 * L0);
  float C2 = PA2 + LA2 + 0.5f * (P1 * L2 - P2 * L1);

  if (p0 <= 999) {
#pragma unroll
    for (int i = 0; i < 4; ++i) {
      int p = p0 + i;
      if (p > 999) break;
      float n0 = bp0 + zs[p * 3 + 0] * scale;
      float n1 = bp1 + zs[p * 3 + 1] * scale;
      float n2 = bp2 + zs[p * 3 + 2] * scale;
      C0 += 0.5f * (bp0 * n1 - bp1 * n0);
      C1 += 0.5f * (bp0 * n2 - bp2 * n0);
      C2 += 0.5f * (bp1 * n2 - bp2 * n1);
      bp0 = n0; bp1 = n1; bp2 = n2;
      if (p % 50 == 0) {
        int s = p / 50;
        Cs[s][0] = C0; Cs[s][1] = C1; Cs[s][2] = C2;
      }
      int k = myfe[i];
      if (k >= 0) {
        earr[k][0] = bp0; earr[k][1] = bp1; earr[k][2] = bp2;
        earr[k][3] = C0;  earr[k][4] = C1;  earr[k][5] = C2;
      }
    }
  }
  __syncthreads();

  if (tid < 63) {
    int s = sc.starts[tid] / 50;
    half8 v = {};
    v[0] = (f16)earr[tid][0]; v[1] = (f16)earr[tid][1]; v[2] = (f16)earr[tid][2];
    v[3] = (f16)(earr[tid][3] - Cs[s][0]);
    v[4] = (f16)(earr[tid][4] - Cs[s][1]);
    v[5] = (f16)(earr[tid][5] - Cs[s][2]);
    half8 zz = {};
    half8* d = (half8*)(lsh + ((size_t)(tid + 1) * BATCH + b) * 64);
    d[0] = v;
#pragma unroll
    for (int q = 1; q < 8; ++q) d[q] = zz;
  } else if (tid == 63) {
    half8 zz = {};
    half8* d = (half8*)(lsh + (size_t)b * 64);
#pragma unroll
    for (int q = 0; q < 8; ++q) d[q] = zz;
  }
}

// ---------------------------------------------------------------------------
// One-shot f32 -> f16 convert of all three weight matrices (K zero-padded).
// ---------------------------------------------------------------------------
__global__ __launch_bounds__(256)
void cvt_all(const float* __restrict__ W1, const float* __restrict__ W2,
             const float* __restrict__ W3, ushort* __restrict__ W1h,
             ushort* __restrict__ W2h, ushort* __restrict__ W3h) {
  const int n1 = HID * (576 / 8);
  const int n2 = HID * (HID / 8);
  int i = blockIdx.x * 256 + threadIdx.x;
  const float* src; ushort* dst; int Ks, Kd;
  if (i < n1)           { src = W1; dst = W1h; Ks = KIN; Kd = 576; }
  else if (i < n1 + n2) { src = W2; dst = W2h; Ks = HID; Kd = HID; i -= n1; }
  else if (i < n1 + 2 * n2) { src = W3; dst = W3h; Ks = HID; Kd = HID; i -= n1 + n2; }
  else return;
  int nblk = Kd >> 3;
  int row = i / nblk, k = (i - row * nblk) * 8;
  half8 v;
#pragma unroll
  for (int j = 0; j < 8; ++j) {
    int kk = k + j;
    float f = (kk < Ks) ? src[(size_t)row * Ks + kk] : 0.f;
    v[j] = (f16)f;
  }
  *(half8*)&dst[(size_t)row * Kd + k] = v;
}

// ---------------------------------------------------------------------------
// Fused 3-layer round with r13's LDS pipeline per layer: global_load_lds
// staging + XOR swizzle + counted vmcnt(8) + raw barriers (3.5us/layer class),
// and r14's validated relaxed-flag slab sync at the 2 layer boundaries.
// Blocks (slab x 128-col strip); all 4 strips of a slab on ONE XCD
// (id%8 == slab%8). K-order identical to r13 -> bit-identical numerics.
// ---------------------------------------------------------------------------
template<int FIRST>
__global__ __launch_bounds__(256)
void fused3(const ushort* __restrict__ carry, const ushort* __restrict__ lsh,
            TL tl,
            const ushort* __restrict__ W1h, const ushort* __restrict__ W2h,
            const ushort* __restrict__ W3h,
            const float* __restrict__ b1, const float* __restrict__ b2,
            const float* __restrict__ b3,
            ushort* __restrict__ act1, ushort* __restrict__ act2,
            ushort* __restrict__ Hall, int* flags, Targ tg) {
  __shared__ ushort lds[32768];                   // 64KB: 2 x (X 16K | W 16K)
  char* ldsb = (char*)lds;
  const int tid = threadIdx.x;
  const int wv = tid >> 6, ln = tid & 63;
  const int slab = blockIdx.x;                    // XCD = slab % 8
  const int bn0 = blockIdx.y * 128;               // col strip
  const int slot = slab >> 3;
  const int t = tl.t[slot], gated = tl.gf[slot];
  const int b0 = (slab & 7) * 128;                // batch-row base
  const size_t gr0 = (size_t)slab * 128;          // act-row base
  const int xr0 = (wv >> 1) * 64, nr0 = (wv & 1) * 64;
  const int l15 = ln & 15, l4 = ln >> 4;
  const int targ = tg.v[slab];
  const ushort* lbase = lsh + (size_t)t * BATCH * 64;

  f32x4 acc[4][4];

  // one r13-style pipelined GEMM layer; xsrc(kt, r, ss) -> global src ptr
  auto gemm = [&](auto xsrc, const ushort* W, int ldw, int k0, int nk) {
#pragma unroll
    for (int mi = 0; mi < 4; ++mi)
#pragma unroll
      for (int ni = 0; ni < 4; ++ni) acc[mi][ni] = (f32x4){0.f, 0.f, 0.f, 0.f};

    auto stage = [&](int bi, int kt) {
#pragma unroll
      for (int i = 0; i < 4; ++i) {
        int qq = (i * 4 + wv) * 64 + ln;
        int r = qq >> 3, sl = qq & 7, ss = sl ^ (r & 7);
        const ushort* src = xsrc(kt, r, ss);
        __builtin_amdgcn_global_load_lds(
            (const __attribute__((address_space(1))) unsigned int*)src,
            (__attribute__((address_space(3))) unsigned int*)
                (ldsb + bi * 32768 + (i * 4 + wv) * 1024), 16, 0, 0);
      }
#pragma unroll
      for (int i = 0; i < 4; ++i) {
        int qq = (i * 4 + wv) * 64 + ln;
        int r = qq >> 3, sl = qq & 7, ss = sl ^ (r & 7);
        const ushort* src = W + (size_t)(bn0 + r) * ldw + kt * 64 + ss * 8;
        __builtin_amdgcn_global_load_lds(
            (const __attribute__((address_space(1))) unsigned int*)src,
            (__attribute__((address_space(3))) unsigned int*)
                (ldsb + bi * 32768 + 16384 + (i * 4 + wv) * 1024), 16, 0, 0);
      }
    };

    stage(0, k0);
    int cur = 0;
    for (int kt = k0; kt < nk; ++kt) {
      if (kt + 1 < nk) {
        stage(cur ^ 1, kt + 1);                   // 8 more loads in flight
        asm volatile("s_waitcnt vmcnt(8)" ::: "memory");
      } else {
        asm volatile("s_waitcnt vmcnt(0)" ::: "memory");
      }
      __builtin_amdgcn_s_barrier();
      __builtin_amdgcn_sched_barrier(0);
#pragma unroll
      for (int kk = 0; kk < 2; ++kk) {
        half8 xf[4], wf[4];
#pragma unroll
        for (int mi = 0; mi < 4; ++mi) {
          int r = xr0 + mi * 16 + l15;
          int ss = (kk * 4 + l4) ^ (r & 7);
          xf[mi] = *(const half8*)(ldsb + cur * 32768 + r * 128 + ss * 16);
        }
#pragma unroll
        for (int ni = 0; ni < 4; ++ni) {
          int r = nr0 + ni * 16 + l15;
          int ss = (kk * 4 + l4) ^ (r & 7);
          wf[ni] = *(const half8*)(ldsb + cur * 32768 + 16384 + r * 128 + ss * 16);
        }
#pragma unroll
        for (int mi = 0; mi < 4; ++mi)
#pragma unroll
          for (int ni = 0; ni < 4; ++ni)
            acc[mi][ni] = __builtin_amdgcn_mfma_f32_16x16x32_f16(
                wf[ni], xf[mi], acc[mi][ni], 0, 0, 0);
      }
      __builtin_amdgcn_sched_barrier(0);
      asm volatile("s_waitcnt lgkmcnt(0)" ::: "memory");
      __builtin_amdgcn_s_barrier();
      cur ^= 1;
    }
  };

#define EPILOGUE(ACT, BIAS, STORE_STMT)                                       \
  do {                                                                        \
    _Pragma("unroll")                                                         \
    for (int mi = 0; mi < 4; ++mi) {                                          \
      _Pragma("unroll")                                                       \
      for (int ni = 0; ni < 4; ++ni) {                                        \
        int col = bn0 + nr0 + ni * 16 + l4 * 4;                               \
        float4 bv = *(const float4*)&(BIAS)[col];                             \
        float bb[4] = {bv.x, bv.y, bv.z, bv.w};                               \
        union { f16 h[4]; u16x4 u; } cv;                                      \
        _Pragma("unroll")                                                     \
        for (int j4 = 0; j4 < 4; ++j4) {                                      \
          float v = acc[mi][ni][j4] + bb[j4];                                 \
          if (ACT == 1) v = fmaxf(v, 0.f);                                    \
          else { float xc = fminf(fmaxf(v, -9.f), 9.f);                       \
                 float e = __expf(2.f * xc); v = (e - 1.f) / (e + 1.f); }     \
          cv.h[j4] = (f16)v;                                                  \
        }                                                                     \
        STORE_STMT;                                                           \
      }                                                                       \
    }                                                                         \
  } while (0)

#define SYNCSLAB(FI)                                                          \
  do {                                                                        \
    asm volatile("s_waitcnt vmcnt(0)" ::: "memory");                          \
    __syncthreads();                                                          \
    if (tid == 0) {                                                           \
      __hip_atomic_fetch_add(&flags[FI], 1, __ATOMIC_RELAXED,                 \
                             __HIP_MEMORY_SCOPE_AGENT);                       \
      while (__hip_atomic_load(&flags[FI], __ATOMIC_RELAXED,                  \
                               __HIP_MEMORY_SCOPE_AGENT) < targ)              \
        __builtin_amdgcn_s_sleep(2);                                          \
    }                                                                         \
    __syncthreads();                                                          \
  } while (0)

  // ---------------- layer 1: [h | ls_t] @ W1^T, relu -> act1 ----------------
  if (FIRST) {
    gemm([&](int kt, int r, int ss) {
      (void)kt; return lbase + (size_t)(b0 + r) * 64 + ss * 8;
    }, W1h, 576, 8, 9);
  } else {
    gemm([&](int kt, int r, int ss) {
      int b_ = b0 + r;
      return (kt < 8) ? carry + (size_t)b_ * HID + kt * 64 + ss * 8
                      : lbase + (size_t)b_ * 64 + ss * 8;
    }, W1h, 576, 0, 9);
  }
  EPILOGUE(1, b1,
    *(u16x4*)&act1[(gr0 + xr0 + mi * 16 + l15) * 512 + col] = cv.u);
  SYNCSLAB(slab);

  // ---------------- layer 2: relu -> act2 ----------------
  gemm([&](int kt, int r, int ss) {
    return act1 + (gr0 + r) * (size_t)HID + kt * 64 + ss * 8;
  }, W2h, 512, 0, 8);
  EPILOGUE(1, b2,
    *(u16x4*)&act2[(gr0 + xr0 + mi * 16 + l15) * 512 + col] = cv.u);
  SYNCSLAB(64 + slab);

  // ---------------- layer 3: tanh -> Hall[t] ----------------
  gemm([&](int kt, int r, int ss) {
    return act2 + (gr0 + r) * (size_t)HID + kt * 64 + ss * 8;
  }, W3h, 512, 0, 8);
  EPILOGUE(2, b3,
    { size_t hrow = (size_t)t * BATCH + b0 + xr0 + mi * 16 + l15;
      u16x4* dst = (u16x4*)&Hall[hrow * 512 + col];
      if (gated) *dst = cv.u;
      else       __builtin_nontemporal_store(cv.u, dst); });
#undef EPILOGUE
#undef SYNCSLAB
}

// ---------------------------------------------------------------------------
// out[b, t, :] = Hall[t][b][:] @ Wout^T. 4 lanes per row, shfl reduce.
// ---------------------------------------------------------------------------
__global__ __launch_bounds__(256)
void out_k(const ushort* __restrict__ Hall, const float* __restrict__ Wout,
           float* __restrict__ out) {
  const int tid = threadIdx.x;
  const int lane4 = tid & 3;
  const int row = blockIdx.x * 64 + (tid >> 2);   // t*1024 + b
  const int t = row >> 10, b = row & 1023;
  const ushort* hb = Hall + (size_t)row * HID;
  float a0 = 0.f, a1 = 0.f, a2 = 0.f;
#pragma unroll 4
  for (int q = 0; q < 16; ++q) {
    int k = (q * 4 + lane4) * 8;
    half8 hv8 = *(const half8*)&hb[k];
#pragma unroll
    for (int j = 0; j < 8; ++j) {
      float h = (float)hv8[j];
      a0 += h * Wout[k + j];
      a1 += h * Wout[512 + k + j];
      a2 += h * Wout[1024 + k + j];
    }
  }
  a0 += __shfl_xor(a0, 1); a0 += __shfl_xor(a0, 2);
  a1 += __shfl_xor(a1, 1); a1 += __shfl_xor(a1, 2);
  a2 += __shfl_xor(a2, 1); a2 += __shfl_xor(a2, 2);
  if (lane4 == 0) {
    float* o = out + ((size_t)b * WIN + t) * 3;
    o[0] = a0; o[1] = a1; o[2] = a2;
  }
}

// ---------------------------------------------------------------------------
extern "C" void kernel_launch(void* const* d_in, const int* in_sizes, int n_in,
                              void* d_out, int out_size, void* d_ws, size_t ws_size,
                              hipStream_t stream) {
  (void)n_in; (void)out_size; (void)ws_size; (void)in_sizes;
  const float* z    = (const float*)d_in[0];
  const float* W1   = (const float*)d_in[1];
  const float* b1   = (const float*)d_in[2];
  const float* W2   = (const float*)d_in[3];
  const float* b2   = (const float*)d_in[4];
  const float* W3   = (const float*)d_in[5];
  const float* b3   = (const float*)d_in[6];
  const float* Wout = (const float*)d_in[7];
  float* out = (float*)d_out;

  // ---- replicate _static_schedule exactly (numpy linspace doubles) ----
  double tb[1000], tt[64], tu[20];
  {
    double sb = 1.0 / 999.0; for (int i = 0; i < 1000; ++i) tb[i] = i * sb; tb[999] = 1.0;
    double st = 1.0 / 63.0;  for (int k = 0; k < 64; ++k)  tt[k] = k * st;  tt[63] = 1.0;
    for (int j = 0; j < 20; ++j) tu[j] = tb[50 * j];
  }
  auto ssr = [](const double* a, int n, double v) -> int {
    int lo = 0, hi = n;
    while (lo < hi) { int mid = (lo + hi) >> 1; if (a[mid] <= v) lo = mid + 1; else hi = mid; }
    return lo - 1;
  };
  Sched sc; int gates[64];
  {
    int u_indices[20];
    for (int j = 0; j < 20; ++j) u_indices[j] = ssr(tb, 1000, tu[j]);
    double u_times[80]; int nut = 0; int last = -1;
    for (int k = 1; k < 64; ++k) {
      int it = ssr(tb, 1000, tt[k]);
      int iu = ssr(tu, 20, tt[k]); if (iu < 0) iu = 0;
      if (iu != last) { u_times[nut++] = tu[iu]; last = iu; }
      sc.starts[k - 1] = u_indices[iu];
      sc.ends[k - 1] = it;
    }
    u_times[nut++] = tt[63];
    int qh = 0;
    for (int k = 0; k < 64; ++k) {
      if (qh < nut && tt[k] >= u_times[qh]) { ++qh; gates[k] = 1; } else gates[k] = 0;
    }
  }
  int seg[64], g[64], ng = 0, jlast = -1;
  for (int t = 0; t < WIN; ++t) {
    seg[t] = jlast;
    if (gates[t]) { g[ng] = t; jlast = ng; ++ng; }
  }

  // ---- workspace carve ----
  char* p = (char*)d_ws;
  int* flags   = (int*)p;    p += 128 * 4;
  ushort* lsh  = (ushort*)p; p += (size_t)WIN * BATCH * 64 * 2;        // 8.4 MB
  ushort* W1h  = (ushort*)p; p += (size_t)HID * 576 * 2;
  ushort* W2h  = (ushort*)p; p += (size_t)HID * HID * 2;
  ushort* W3h  = (ushort*)p; p += (size_t)HID * HID * 2;
  ushort* Hall = (ushort*)p; p += (size_t)WIN * BATCH * HID * 2;       // 67 MB
  ushort* act1 = (ushort*)p; p += (size_t)4 * BATCH * HID * 2;         // 4.2 MB
  ushort* act2 = (ushort*)p; p += (size_t)4 * BATCH * HID * 2;

  hipMemsetAsync(flags, 0, 128 * 4, stream);

  float scale = (float)std::sqrt(1.0 / 999.0);
  logsig_scan<<<BATCH, 256, 0, stream>>>(z, sc, lsh, scale);
  cvt_all<<<(HID * 72 + 2 * HID * 64 + 255) / 256, 256, 0, stream>>>(
      W1, W2, W3, W1h, W2h, W3h);

  // ---- serial per-segment rounds: ONE fused 3-layer launch each ----
  Targ tg; for (int i = 0; i < 32; ++i) tg.v[i] = 0;
  for (int r = 0; r < ng; ++r) {
    TL tlr; int cnt = 0;
    for (int t = 0; t < WIN && cnt < 4; ++t)
      if (seg[t] == r - 1) tlr.t[cnt++] = t;
    if (cnt == 0) continue;
    for (int i = cnt; i < 8; ++i) tlr.t[i] = tlr.t[0];
    for (int i = 0; i < 8; ++i) tlr.gf[i] = (tlr.t[i] == g[r]) ? 1 : 0;
    for (int s = 0; s < cnt * 8; ++s) tg.v[s] += 4;     // monotonic targets
    const ushort* carry = (r == 0) ? nullptr : Hall + (size_t)g[r - 1] * (BATCH * HID);
    dim3 gg(cnt * 8, 4), gb(256);
    if (r == 0)
      fused3<1><<<gg, gb, 0, stream>>>(carry, lsh, tlr, W1h, W2h, W3h,
                                       b1, b2, b3, act1, act2, Hall, flags, tg);
    else
      fused3<0><<<gg, gb, 0, stream>>>(carry, lsh, tlr, W1h, W2h, W3h,
                                       b1, b2, b3, act1, act2, Hall, flags, tg);
  }

  out_k<<<WIN * BATCH / 64, 256, 0, stream>>>(Hall, Wout, out);
}